// Round 7
// baseline (992.494 us; speedup 1.0000x reference)
//
#include <hip/hip_runtime.h>
#include <math.h>

#define NA   360
#define ZPT  16
#define ROWS 39           // iv window: span<=34.2 (+floor/bilinear/hull pad)
#define COLS 52
#define NSTG 2048         // 8*256 staged floats: rows 0..39 (last partial)
#define PITCHB (COLS*4)
#define VLO_MAX 216       // keeps staged slab offsets < 65536 elements

// Cone-beam backprojection, LDS-staged via global_load_lds (zero-register).
// Geometry: dz=dy=dx=2mm, dv=du=2mm, DSO=1000, DSD=1536, mag in [1.302,1.872].
// iv = zv*mag + 127.5 in (8.6,246.4) -> v never clamps, v0+1 in-bounds.
// ZPT=16 z-tile: iv-span <= 15*1.872 + 63.5*0.0967 = 34.2 -> 39-row window
// [v_lo, v_lo+38] covers all taps (v_lo = floor(min)-1, clamped [0,216]).
// Max staged global offset: (216+39)*256 + 19 extra < 65536 -> in-slab.
// u window COLS=52 for 16x16 xy tiles proven by R5/R6 exhaustive pass.

typedef __attribute__((address_space(1))) const void gas_t;
typedef __attribute__((address_space(3))) void las_t;

__device__ __forceinline__ int2 bbox_angle(float c, float s,
    float xclo, float xchi, float yclo, float ychi, float zvlo, float zvhi)
{
    const float a0 = xclo*c, a1 = xchi*c, b0 = yclo*s, b1 = ychi*s;
    const float xr0 = a0+b0, xr1 = a0+b1, xr2 = a1+b0, xr3 = a1+b1;
    const float xmn = fminf(fminf(xr0,xr1), fminf(xr2,xr3));
    const float xmx = fmaxf(fmaxf(xr0,xr1), fmaxf(xr2,xr3));
    const float c0 = yclo*c, c1 = ychi*c, d0 = xclo*s, d1 = xchi*s;
    const float yr0 = c0-d0, yr1 = c0-d1, yr2 = c1-d0, yr3 = c1-d1;
    const float ymn = fminf(fminf(yr0,yr1), fminf(yr2,yr3));
    const float ymx = fmaxf(fmaxf(yr0,yr1), fmaxf(yr2,yr3));
    const float mlo = 1536.f * __builtin_amdgcn_rcpf(1000.f - xmn);
    const float mhi = 1536.f * __builtin_amdgcn_rcpf(1000.f - xmx);
    const float umn = fminf(fminf(ymn*mlo, ymn*mhi), fminf(ymx*mlo, ymx*mhi));
    int u_lo = (int)floorf(fmaf(umn, 0.5f, 127.5f)) - 1;
    u_lo = u_lo < 0 ? 0 : (u_lo > 256-COLS ? 256-COLS : u_lo);
    const float vmn = fminf(fminf(zvlo*mlo, zvlo*mhi), fminf(zvhi*mlo, zvhi*mhi));
    int v_lo = (int)floorf(vmn + 127.5f) - 1;
    v_lo = v_lo < 0 ? 0 : (v_lo > VLO_MAX ? VLO_MAX : v_lo);
    return make_int2(u_lo, v_lo);
}

__device__ __forceinline__ void stage8(const char* gb, float* lds_wave,
                                       const int goffB[8]) {
    #pragma unroll
    for (int i = 0; i < 8; ++i) {
        __builtin_amdgcn_global_load_lds(
            (gas_t*)(gb + goffB[i]),
            (las_t*)(lds_wave + i * 256),
            4, 0, 0);
    }
}

__device__ __forceinline__ void compute_angle(const float* __restrict__ smb,
    float c, float s, float xc, float yc, float zf0, int u_lo, int v_lo,
    float acc[ZPT])
{
    const float xr  = xc*c + yc*s;
    const float yr  = yc*c - xc*s;
    const float mag = 1536.f * __builtin_amdgcn_rcpf(1000.f - xr);
    const float iu  = fmaf(yr*mag, 0.5f, 127.5f);
    const bool uval = (iu >= 0.f) && (iu <= 255.f);
    const float iuc = fminf(fmaxf(iu, 0.f), 255.f);
    int u0 = (int)iuc; u0 = u0 > 254 ? 254 : u0;
    const float fu  = iuc - (float)u0;
    const float w   = uval ? 1.f : 0.f;
    const float wu1 = fu*w, wu0 = w - wu1;
    const int   ub  = (u0 - u_lo) << 2;                 // byte offset in row
    const float ivb = fmaf(zf0, mag, 127.5f) - (float)v_lo;
    #pragma unroll
    for (int k = 0; k < ZPT; ++k) {
        const float ivl = fmaf((float)k, mag, ivb);
        const int   v0  = (int)ivl;                     // >0 -> trunc==floor
        const float fv  = ivl - (float)v0;
        const char* p   = (const char*)smb + (v0*PITCHB + ub);
        const float p00 = *(const float*)p;
        const float p01 = *(const float*)(p + 4);
        const float p10 = *(const float*)(p + PITCHB);
        const float p11 = *(const float*)(p + PITCHB + 4);
        const float q0 = fmaf(fv, p10 - p00, p00);
        const float q1 = fmaf(fv, p11 - p01, p01);
        acc[k] = fmaf(wu0, q0, acc[k]);
        acc[k] = fmaf(wu1, q1, acc[k]);
    }
}

__global__ __launch_bounds__(256, 4) void bp_kernel(const float* __restrict__ proj,
                                                    float* __restrict__ out) {
    __shared__ float2 cs_sh[NA];
    __shared__ int2   bb_sh[NA];
    __shared__ float  patch[2][NSTG];

    const int tid = threadIdx.y * 16 + threadIdx.x;

    const int zg = blockIdx.x;            // z-group
    const int t  = blockIdx.y;            // xy tile
    const int b  = blockIdx.z;
    const int x0 = (t & 7) * 16;
    const int y0 = (t >> 3) * 16;
    const int zb = zg * ZPT;

    const float zf0  = (float)zb - 63.5f;
    const float xclo = ((float)x0 - 63.5f) * 2.f, xchi = xclo + 30.f;
    const float yclo = ((float)y0 - 63.5f) * 2.f, ychi = yclo + 30.f;

    for (int i = tid; i < NA; i += 256) {
        float th = (float)i * (float)(2.0 * M_PI / (double)NA);
        float sv, cv; sincosf(th, &sv, &cv);
        cs_sh[i] = make_float2(cv, sv);
        bb_sh[i] = bbox_angle(cv, sv, xclo, xchi, yclo, ychi, zf0, zf0 + 15.f);
    }
    __syncthreads();

    // staging pattern: flat patch idx = tid + 256*i, patch is [40][52] row-major
    int goffB[8];
    #pragma unroll
    for (int i = 0; i < 8; ++i) {
        const int flat = tid + 256 * i;
        const int r  = flat / 52;             // compiler magic-mul, exact
        const int cc = flat - r * 52;
        goffB[i] = (r * 256 + cc) * 4;        // detector-row-major, bytes
    }

    const float* projB = proj + (size_t)b * (NA * 65536);
    const float xc = ((float)(x0 + threadIdx.x) - 63.5f) * 2.f;
    const float yc = ((float)(y0 + threadIdx.y) - 63.5f) * 2.f;

    float* wv0 = &patch[0][tid & 192];        // wave-uniform LDS bases
    float* wv1 = &patch[1][tid & 192];

    float acc[ZPT];
    #pragma unroll
    for (int k = 0; k < ZPT; ++k) acc[k] = 0.f;

    // prologue: stage angle 0 into patch[0]
    {
        const int2 lo = bb_sh[0];
        const uint32_t aoffB = __builtin_amdgcn_readfirstlane(
            (uint32_t)((lo.y << 8) + lo.x) << 2);
        stage8((const char*)projB + aoffB, wv0, goffB);
    }
    __syncthreads();   // drains vmcnt -> patch[0] ready

    for (int a = 0; a < NA; a += 2) {
        {   // stage a+1 -> patch[1] while computing a from patch[0]
            const int2 lo = bb_sh[a + 1];
            const uint32_t aoffB = __builtin_amdgcn_readfirstlane(
                (uint32_t)(((a + 1) << 16) + (lo.y << 8) + lo.x) << 2);
            stage8((const char*)projB + aoffB, wv1, goffB);
        }
        {
            const float2 cs = cs_sh[a];
            const int2   lo = bb_sh[a];
            compute_angle(patch[0], cs.x, cs.y, xc, yc, zf0, lo.x, lo.y, acc);
        }
        __syncthreads();
        if (a + 2 < NA) {   // stage a+2 -> patch[0] while computing a+1
            const int2 lo = bb_sh[a + 2];
            const uint32_t aoffB = __builtin_amdgcn_readfirstlane(
                (uint32_t)(((a + 2) << 16) + (lo.y << 8) + lo.x) << 2);
            stage8((const char*)projB + aoffB, wv0, goffB);
        }
        {
            const float2 cs = cs_sh[a + 1];
            const int2   lo = bb_sh[a + 1];
            compute_angle(patch[1], cs.x, cs.y, xc, yc, zf0, lo.x, lo.y, acc);
        }
        __syncthreads();
    }

    float* o = out + (((size_t)b * 128 + zb) * 128 + (y0 + threadIdx.y)) * 128
                   + (x0 + threadIdx.x);
    #pragma unroll
    for (int k = 0; k < ZPT; ++k) {
        o[(size_t)k * (128 * 128)] = acc[k];
    }
}

extern "C" void kernel_launch(void* const* d_in, const int* in_sizes, int n_in,
                              void* d_out, int out_size, void* d_ws, size_t ws_size,
                              hipStream_t stream) {
    const float* proj = (const float*)d_in[0];
    float* out = (float*)d_out;
    dim3 grid(128 / ZPT, 64, 2);   // (z-groups, xy-tiles, batch) = 1024 blocks
    dim3 block(16, 16, 1);
    hipLaunchKernelGGL(bp_kernel, grid, block, 0, stream, proj, out);
}

// Round 8
// 814.577 us; speedup vs baseline: 1.2184x; 1.2184x over previous
//
#include <hip/hip_runtime.h>
#include <math.h>

#define NA    360
#define ZPT   8
#define PROWS 32          // v window (need 24: span 19.24 + floor/bilinear/hull pad)
#define PCOLS 64          // u window (need 52, proven R5/R6 exhaustive)
#define NSTG  (PROWS*PCOLS)   // 2048 floats = 8KB per buffer
#define VLO_MAX 224       // (224+31)*256 + 192+63 = 65535: staged reads stay in-slab
#define ULO_MAX 192

// Cone-beam backprojection, LDS-staged via width-16 global_load_lds.
// Geometry: dz=dy=dx=2mm, dv=du=2mm, DSO=1000, DSD=1536, mag in [1.302,1.872].
// iv = zv*mag + 127.5 in (8.6,246.4) -> v never clamps, v0+1 in-bounds.
// Patch [32][64] f32: each row is a 256B contiguous run of the detector row
// -> whole patch staged by 8 wave-wide dwordx4 global_load_lds (2 per wave),
// per-lane voffset constant across angles; per-angle base is SGPR-only.

typedef float v2f __attribute__((ext_vector_type(2)));
typedef __attribute__((address_space(1))) const void gas_t;
typedef __attribute__((address_space(3))) void las_t;

__device__ __forceinline__ int2 bbox_angle(float c, float s,
    float xclo, float xchi, float yclo, float ychi, float zvlo, float zvhi)
{
    const float a0 = xclo*c, a1 = xchi*c, b0 = yclo*s, b1 = ychi*s;
    const float xr0 = a0+b0, xr1 = a0+b1, xr2 = a1+b0, xr3 = a1+b1;
    const float xmn = fminf(fminf(xr0,xr1), fminf(xr2,xr3));
    const float xmx = fmaxf(fmaxf(xr0,xr1), fmaxf(xr2,xr3));
    const float c0 = yclo*c, c1 = ychi*c, d0 = xclo*s, d1 = xchi*s;
    const float yr0 = c0-d0, yr1 = c0-d1, yr2 = c1-d0, yr3 = c1-d1;
    const float ymn = fminf(fminf(yr0,yr1), fminf(yr2,yr3));
    const float ymx = fmaxf(fmaxf(yr0,yr1), fmaxf(yr2,yr3));
    const float mlo = 1536.f * __builtin_amdgcn_rcpf(1000.f - xmn);
    const float mhi = 1536.f * __builtin_amdgcn_rcpf(1000.f - xmx);
    const float umn = fminf(fminf(ymn*mlo, ymn*mhi), fminf(ymx*mlo, ymx*mhi));
    int u_lo = (int)floorf(fmaf(umn, 0.5f, 127.5f)) - 1;
    u_lo = u_lo < 0 ? 0 : (u_lo > ULO_MAX ? ULO_MAX : u_lo);
    const float vmn = fminf(fminf(zvlo*mlo, zvlo*mhi), fminf(zvhi*mlo, zvhi*mhi));
    int v_lo = (int)floorf(vmn + 127.5f) - 1;
    v_lo = v_lo < 0 ? 0 : (v_lo > VLO_MAX ? VLO_MAX : v_lo);
    return make_int2(u_lo, v_lo);
}

__device__ __forceinline__ void stage2(const char* gb, int vb0, int vb1,
                                       float* l0, float* l1) {
    __builtin_amdgcn_global_load_lds((gas_t*)(gb + vb0), (las_t*)l0, 16, 0, 0);
    __builtin_amdgcn_global_load_lds((gas_t*)(gb + vb1), (las_t*)l1, 16, 0, 0);
}

__device__ __forceinline__ void compute_angle(const float* __restrict__ smb,
    float c, float s, float xc, float yc, float zf0, int u_lo, int v_lo,
    v2f acc[ZPT])
{
    const float xr  = xc*c + yc*s;
    const float yr  = yc*c - xc*s;
    const float mag = 1536.f * __builtin_amdgcn_rcpf(1000.f - xr);
    const float iu  = fmaf(yr*mag, 0.5f, 127.5f);
    const bool uval = (iu >= 0.f) && (iu <= 255.f);
    const float iuc = fminf(fmaxf(iu, 0.f), 255.f);
    int u0 = (int)iuc; u0 = u0 > 254 ? 254 : u0;
    const float fu  = iuc - (float)u0;
    const float w   = uval ? 1.f : 0.f;
    const float wu1 = fu*w, wu0 = w - wu1;
    const v2f   wuv = {wu0, wu1};
    const int   ui  = u0 - u_lo;                         // 0..62
    const float ivb = fmaf(zf0, mag, 127.5f) - (float)v_lo;
    #pragma unroll
    for (int k = 0; k < ZPT; ++k) {
        const float ivl = fmaf((float)k, mag, ivb);
        const int   v0  = (int)ivl;                      // >0 -> trunc==floor
        const float fv  = ivl - (float)v0;
        const float* r  = smb + ((v0 << 6) + ui);
        v2f p0 = {r[0],  r[1]};                          // row v0  (ds_read2)
        v2f p1 = {r[64], r[65]};                         // row v0+1
        const v2f fvv = {fv, fv};
        const v2f q = __builtin_elementwise_fma(fvv, p1 - p0, p0);
        acc[k] = __builtin_elementwise_fma(wuv, q, acc[k]);
    }
}

__global__ __launch_bounds__(256, 4) void bp_kernel(const float* __restrict__ proj,
                                                    float* __restrict__ out) {
    __shared__ float2 cs_sh[NA];
    __shared__ int2   bb_sh[NA];
    __shared__ float  patch[2][NSTG];

    const int tid = threadIdx.y * 16 + threadIdx.x;

    const int zg = blockIdx.x;            // z-group (16)
    const int t  = blockIdx.y;            // xy tile (64)
    const int b  = blockIdx.z;
    const int x0 = (t & 7) * 16;
    const int y0 = (t >> 3) * 16;
    const int zb = zg * ZPT;

    const float zf0  = (float)zb - 63.5f;
    const float xclo = ((float)x0 - 63.5f) * 2.f, xchi = xclo + 30.f;
    const float yclo = ((float)y0 - 63.5f) * 2.f, ychi = yclo + 30.f;

    for (int i = tid; i < NA; i += 256) {
        float th = (float)i * (float)(2.0 * M_PI / (double)NA);
        float sv, cv; sincosf(th, &sv, &cv);
        cs_sh[i] = make_float2(cv, sv);
        bb_sh[i] = bbox_angle(cv, sv, xclo, xchi, yclo, ychi, zf0, zf0 + 7.f);
    }
    __syncthreads();

    // Constant per-lane staging voffsets: lane covers patch-flat idx lane*4..+3;
    // global offset = (row(lane>>4)*256 + col(lane&15)*4) floats within window.
    const int lane = tid & 63;
    const int vb0  = ((lane >> 4) * 256 + (lane & 15) * 4) * 4;  // bytes
    const int vb1  = vb0 + 4096;                                  // second chunk (+4 rows)
    // Wave w stages patch-flat [w*2048 .. w*2048+2047] bytes... chunks w*2+{0,1}.
    const uint32_t wslab = __builtin_amdgcn_readfirstlane((uint32_t)(tid >> 6) * 8192u);

    const char* projB = (const char*)(proj + (size_t)b * (NA * 65536));
    const float xc = ((float)(x0 + threadIdx.x) - 63.5f) * 2.f;
    const float yc = ((float)(y0 + threadIdx.y) - 63.5f) * 2.f;

    float* l0a = &patch[0][(tid >> 6) * 512];
    float* l0b = l0a + 256;
    float* l1a = &patch[1][(tid >> 6) * 512];
    float* l1b = l1a + 256;

    v2f acc[ZPT];
    #pragma unroll
    for (int k = 0; k < ZPT; ++k) acc[k] = (v2f){0.f, 0.f};

    // prologue: stage angle 0 into patch[0]
    {
        const int2 lo = bb_sh[0];
        const uint32_t boff = __builtin_amdgcn_readfirstlane(
            ((uint32_t)lo.y << 10) + ((uint32_t)lo.x << 2));
        stage2(projB + (boff + wslab), vb0, vb1, l0a, l0b);
    }
    __syncthreads();   // implicit vmcnt(0) drain -> patch[0] ready

    for (int a = 0; a < NA; a += 2) {
        {   // stage a+1 -> patch[1] while computing a from patch[0]
            const int2 lo = bb_sh[a + 1];
            const uint32_t boff = __builtin_amdgcn_readfirstlane(
                ((uint32_t)lo.y << 10) + ((uint32_t)lo.x << 2));
            stage2(projB + ((uint32_t)(a + 1) * 262144u + boff + wslab), vb0, vb1, l1a, l1b);
        }
        {
            const float2 cs = cs_sh[a];
            const int2   lo = bb_sh[a];
            compute_angle(patch[0], cs.x, cs.y, xc, yc, zf0, lo.x, lo.y, acc);
        }
        __syncthreads();
        if (a + 2 < NA) {   // stage a+2 -> patch[0] while computing a+1
            const int2 lo = bb_sh[a + 2];
            const uint32_t boff = __builtin_amdgcn_readfirstlane(
                ((uint32_t)lo.y << 10) + ((uint32_t)lo.x << 2));
            stage2(projB + ((uint32_t)(a + 2) * 262144u + boff + wslab), vb0, vb1, l0a, l0b);
        }
        {
            const float2 cs = cs_sh[a + 1];
            const int2   lo = bb_sh[a + 1];
            compute_angle(patch[1], cs.x, cs.y, xc, yc, zf0, lo.x, lo.y, acc);
        }
        __syncthreads();
    }

    float* o = out + (((size_t)b * 128 + zb) * 128 + (y0 + threadIdx.y)) * 128
                   + (x0 + threadIdx.x);
    #pragma unroll
    for (int k = 0; k < ZPT; ++k) {
        o[(size_t)k * (128 * 128)] = acc[k].x + acc[k].y;
    }
}

extern "C" void kernel_launch(void* const* d_in, const int* in_sizes, int n_in,
                              void* d_out, int out_size, void* d_ws, size_t ws_size,
                              hipStream_t stream) {
    const float* proj = (const float*)d_in[0];
    float* out = (float*)d_out;
    dim3 grid(128 / ZPT, 64, 2);   // (z-groups, xy-tiles, batch) = 2048 blocks
    dim3 block(16, 16, 1);
    hipLaunchKernelGGL(bp_kernel, grid, block, 0, stream, proj, out);
}